// Round 7
// baseline (69.441 us; speedup 1.0000x reference)
//
#include <hip/hip_runtime.h>
#include <math.h>

constexpr int BN = 8192;
constexpr int MN = 6;

// E = -T*log2(e)*d2 with T=2:  E = 2TL*g - TL*sq_i - TL*sq_j,  L=log2(e)
constexpr float TL    = 2.8853900817779268f;   // 2*log2(e)
constexpr float SCL_Z = 2.4022448795936154f;   // sqrt(2*T*L)

typedef __bf16 bf16_t;
typedef bf16_t bf16x8 __attribute__((ext_vector_type(8)));
typedef float f32x4 __attribute__((ext_vector_type(4)));

union PK { bf16_t h[8]; uint4 u; };

__device__ __forceinline__ bf16x8 frag_of(uint4 u) {
    return __builtin_bit_cast(bf16x8, u);
}

__device__ __host__ __forceinline__ int midx(int a, int b) {
    // index into upper-triangle (a<=b) of 8x8, row-major packed
    return 8 * a - (a * (a - 1)) / 2 + (b - a);
}

// ---------------------------------------------------------------------------
// K0: blocks 0..191  -> pack MFMA fragments (one thread per (mode, row)).
//     blocks 192..223 -> angle second moments (36 pair moments + 8 sums).
// ---------------------------------------------------------------------------
__global__ __launch_bounds__(256) void prep_ang(const float* __restrict__ x,
                                                const float* __restrict__ ang,
                                                uint4* __restrict__ Ap,
                                                uint4* __restrict__ Bp,
                                                float* __restrict__ angp) {
    const int blk = blockIdx.x;
    const int tid = threadIdx.x;
    if (blk < 192) {
        int idx = blk * 256 + tid;
        int n = idx >> 13;
        int j = idx & (BN - 1);
        const float* p = x + (size_t)j * 48 + n * 8;

        PK zh, zl, a3, b3;
        float sq = 0.f;
#pragma unroll
        for (int k = 0; k < 8; ++k) {
            float v = p[k];
            sq = fmaf(v, v, sq);
            float z = SCL_Z * v;
            bf16_t h = (bf16_t)z;
            zh.h[k] = h;
            zl.h[k] = (bf16_t)(z - (float)h);
        }
        float s = -TL * sq;
        bf16_t sh = (bf16_t)s;
        bf16_t sl = (bf16_t)(s - (float)sh);
        bf16_t one = (bf16_t)1.0f, zero = (bf16_t)0.0f;
        a3.h[0] = one; a3.h[1] = one; a3.h[2] = sh;  a3.h[3] = sl;
        b3.h[0] = sh;  b3.h[1] = sl;  b3.h[2] = one; b3.h[3] = one;
#pragma unroll
        for (int k = 4; k < 8; ++k) { a3.h[k] = zero; b3.h[k] = zero; }

        size_t base = ((size_t)(n * 512 + (j >> 4))) * 64 + (j & 15);
        Ap[base +  0] = zh.u;
        Ap[base + 16] = zl.u;
        Ap[base + 32] = zh.u;
        Ap[base + 48] = a3.u;
        Bp[base +  0] = zh.u;
        Bp[base + 16] = zh.u;
        Bp[base + 32] = zl.u;
        Bp[base + 48] = b3.u;
    } else {
        const int i = (blk - 192) * 256 + tid;  // 32 blocks cover 8192 rows
        float v[8];
#pragma unroll
        for (int k = 0; k < 4; ++k) __sincosf(ang[i * 4 + k], &v[k], &v[4 + k]);
        float acc[44];
        int c = 0;
#pragma unroll
        for (int a = 0; a < 8; ++a)
#pragma unroll
            for (int bq = a; bq < 8; ++bq) acc[c++] = v[a] * v[bq];
#pragma unroll
        for (int a = 0; a < 8; ++a) acc[36 + a] = v[a];

#pragma unroll
        for (int q = 0; q < 44; ++q) {
            float s = acc[q];
            s += __shfl_xor(s, 1);  s += __shfl_xor(s, 2);
            s += __shfl_xor(s, 4);  s += __shfl_xor(s, 8);
            s += __shfl_xor(s, 16); s += __shfl_xor(s, 32);
            acc[q] = s;
        }
        __shared__ float sm[4][44];
        const int w = tid >> 6, lane = tid & 63;
        if (lane == 0)
#pragma unroll
            for (int q = 0; q < 44; ++q) sm[w][q] = acc[q];
        __syncthreads();
        if (tid < 44)
            angp[(blk - 192) * 44 + tid] =
                sm[0][tid] + sm[1][tid] + sm[2][tid] + sm[3][tid];
    }
}

// ---------------------------------------------------------------------------
// K1: pairwise kernel — persistent, wave-independent decomposition.
// 2048 blocks x 256 thr = 8192 waves = exactly 32 waves/CU resident, no tail.
// Work unit u = (mode n, 64-row group rb, 16-col-tile chunk c); 24576 units;
// wave g owns units 3g..3g+2.  No __syncthreads; each unit's 64 row-partials
// are staged through a per-wave LDS strip and stored to a unique Sh slot
// (deterministic, no atomics).  Inner loop register-light (R5 spill lesson).
// ---------------------------------------------------------------------------
__global__ __launch_bounds__(256, 8) void pair_mfma(const uint4* __restrict__ Ap,
                                                    const uint4* __restrict__ Bp,
                                                    float* __restrict__ Sh) {
    const int tid  = threadIdx.x;
    const int lane = tid & 63;
    const int wloc = tid >> 6;
    const int gw   = __builtin_amdgcn_readfirstlane((blockIdx.x * 256 + tid) >> 6);

    __shared__ float smem[4][64];
    const f32x4 z4 = {0.f, 0.f, 0.f, 0.f};

    for (int k = 0; k < 3; ++k) {
        const int u   = gw * 3 + k;
        const int n   = u >> 12;          // mode
        const int rb  = (u >> 5) & 127;   // 64-row group
        const int c   = u & 31;           // 16-tile col chunk
        const int rb4 = rb * 4;

        bf16x8 af[4];
#pragma unroll
        for (int t = 0; t < 4; ++t)
            af[t] = frag_of(Ap[((size_t)(n * 512 + rb4 + t)) * 64 + lane]);

        float racc[16];
#pragma unroll
        for (int q = 0; q < 16; ++q) racc[q] = 0.f;

        const uint4* bbase = Bp + ((size_t)n * 512) * 64 + lane;
        const int jt0 = c * 16;

        uint4 b0 = bbase[(size_t)jt0 * 64];
        uint4 b1 = bbase[(size_t)(jt0 + 1) * 64];
        for (int jt = jt0; jt < jt0 + 16; jt += 2) {
            // depth-2 prefetch; final-iter over-read (<=2 tiles) stays in ws
            uint4 p0 = bbase[(size_t)(jt + 2) * 64];
            uint4 p1 = bbase[(size_t)(jt + 3) * 64];

            bf16x8 bf = frag_of(b0);
#pragma unroll
            for (int t = 0; t < 4; ++t) {
                f32x4 d = __builtin_amdgcn_mfma_f32_16x16x32_bf16(af[t], bf, z4, 0, 0, 0);
#pragma unroll
                for (int r = 0; r < 4; ++r)
                    racc[t * 4 + r] += __builtin_amdgcn_exp2f(d[r]);
            }
            bf = frag_of(b1);
#pragma unroll
            for (int t = 0; t < 4; ++t) {
                f32x4 d = __builtin_amdgcn_mfma_f32_16x16x32_bf16(af[t], bf, z4, 0, 0, 0);
#pragma unroll
                for (int r = 0; r < 4; ++r)
                    racc[t * 4 + r] += __builtin_amdgcn_exp2f(d[r]);
            }
            b0 = p0; b1 = p1;
        }

        // diagonal fix-up: diag tiles rb4..rb4+3 all fall in chunk c == rb>>2
        if (c == (rb >> 2)) {
            const int dd = (lane & 15) - 4 * (lane >> 4);
#pragma unroll
            for (int t = 0; t < 4; ++t) {
                bf16x8 bf = frag_of(bbase[(size_t)(rb4 + t) * 64]);
                f32x4 d = __builtin_amdgcn_mfma_f32_16x16x32_bf16(af[t], bf, z4, 0, 0, 0);
#pragma unroll
                for (int r = 0; r < 4; ++r)
                    if (dd == r) racc[t * 4 + r] -= __builtin_amdgcn_exp2f(d[r]);
            }
        }

        // reduce over the 16 column lanes (low 4 lane bits)
#pragma unroll
        for (int q = 0; q < 16; ++q) {
            float v = racc[q];
            v += __shfl_xor(v, 1);
            v += __shfl_xor(v, 2);
            v += __shfl_xor(v, 4);
            v += __shfl_xor(v, 8);
            racc[q] = v;
        }

        // stage 64 row-partials via this wave's LDS strip, store to Sh slot
        if ((lane & 15) == 0) {
            int g = lane >> 4;
#pragma unroll
            for (int t = 0; t < 4; ++t)
#pragma unroll
                for (int r = 0; r < 4; ++r)
                    smem[wloc][t * 16 + g * 4 + r] = racc[t * 4 + r];
        }
        float val = smem[wloc][lane];  // same-wave RAW: compiler emits lgkmcnt wait
        Sh[(size_t)c * (MN * BN) + n * BN + rb * 64 + lane] = val;
    }
}

// ---------------------------------------------------------------------------
// K2: sum 32 contributor slots per row, take log, per-block partial sums.
// 96 blocks x 512 covering the 6*8192 flat row space (16 blocks per mode).
// ---------------------------------------------------------------------------
__global__ __launch_bounds__(512) void log_red(const float* __restrict__ Sh,
                                               float* __restrict__ lp) {
    const int tid = threadIdx.x;
    const int idx = blockIdx.x * 512 + tid;
    float v = 0.f;
#pragma unroll
    for (int c = 0; c < 32; ++c) v += Sh[(size_t)c * (MN * BN) + idx];
    float lg = logf(v);
    lg += __shfl_xor(lg, 1);
    lg += __shfl_xor(lg, 2);
    lg += __shfl_xor(lg, 4);
    lg += __shfl_xor(lg, 8);
    lg += __shfl_xor(lg, 16);
    lg += __shfl_xor(lg, 32);
    __shared__ float sm[8];
    if ((tid & 63) == 0) sm[tid >> 6] = lg;
    __syncthreads();
    if (tid == 0) {
        float s = 0.f;
#pragma unroll
        for (int i = 0; i < 8; ++i) s += sm[i];
        lp[blockIdx.x] = s;
    }
}

// ---------------------------------------------------------------------------
// K3: final assembly — mu/cov/spread from moments, per-mode unif, outputs.
// ---------------------------------------------------------------------------
__global__ __launch_bounds__(64) void final_asm(const float* __restrict__ angp,
                                                const float* __restrict__ lp,
                                                float* __restrict__ out) {
    const int tid = threadIdx.x;
    __shared__ float mom[44];

    if (tid < 44) {
        float s = 0.f;
        for (int bk = 0; bk < 32; ++bk) s += angp[bk * 44 + tid];
        mom[tid] = s;
    }
    __syncthreads();

    if (tid == 0) {
        float sm[4], cm[4];
#pragma unroll
        for (int k = 0; k < 4; ++k) {
            float S = mom[36 + k], C = mom[40 + k];
            float hyp = sqrtf(S * S + C * C);
            sm[k] = S / hyp;       // sin(mu_k)
            cm[k] = C / hyp;       // cos(mu_k)
        }
        auto COV = [&](int k, int l) -> float {
            int ks = k < l ? k : l, kl = k < l ? l : k;
            float mss = mom[midx(ks, kl)];
            float msc_kl = mom[midx(k, l + 4)];
            float msc_lk = mom[midx(l, k + 4)];
            float mcc = mom[midx(ks + 4, kl + 4)];
            return (cm[k] * cm[l] * mss - cm[k] * sm[l] * msc_kl -
                    sm[k] * cm[l] * msc_lk + sm[k] * sm[l] * mcc) *
                   (1.0f / (float)BN);
        };
        float var[4] = {COV(0, 0), COV(1, 1), COV(2, 2), COV(3, 3)};
        float spread = 0.f;
        const int pk[6] = {0, 0, 0, 1, 1, 2};
        const int pl[6] = {1, 2, 3, 2, 3, 3};
#pragma unroll
        for (int p = 0; p < 6; ++p) {
            float cv = COV(pk[p], pl[p]);
            float den = sqrtf(var[pk[p]] * var[pl[p]] + 1e-8f);
            float cr = cv / den;
            spread += cr * cr;
        }
        spread *= (1.0f / 6.0f);

        const float wgt[6] = {0.0f, 0.19615242270663188f, 0.4641016151377544f,
                              0.7320508075688773f, 0.9282032302755088f, 1.0f};
        const float logBm1 = logf((float)(BN - 1));
        float total_unif = 0.f, unif[6];
#pragma unroll
        for (int m = 0; m < 6; ++m) {
            float s = 0.f;
            for (int i = 0; i < 16; ++i) s += lp[m * 16 + i];
            unif[m] = s * (1.0f / (float)BN) - logBm1;
            total_unif += wgt[m] * unif[m];
        }
        out[0] = total_unif;
        out[1] = spread;
        out[2] = total_unif + spread;
#pragma unroll
        for (int m = 0; m < 6; ++m) out[3 + m] = unif[m];
    }
}

extern "C" void kernel_launch(void* const* d_in, const int* in_sizes, int n_in,
                              void* d_out, int out_size, void* d_ws, size_t ws_size,
                              hipStream_t stream) {
    const float* angles  = (const float*)d_in[0];   // (8192, 4) f32
    const float* fourier = (const float*)d_in[1];   // (8192, 48) f32
    float* out = (float*)d_out;                     // 9 floats

    char* ws = (char*)d_ws;
    uint4* Bp   = (uint4*)(ws + 0);                 // 3,145,728 B
    uint4* Ap   = (uint4*)(ws + 3145728);           // 3,145,728 B (absorbs tail over-read)
    float* Sh   = (float*)(ws + 6291456);           // 32 x 49152 f32 = 6,291,456 B
    float* lp   = (float*)(ws + 12582912);          // 96 f32 log partials
    float* angp = (float*)(ws + 12583296);          // 32*44 f32 angle moments

    prep_ang<<<dim3(224), dim3(256), 0, stream>>>(fourier, angles, Ap, Bp, angp);
    pair_mfma<<<dim3(2048), dim3(256), 0, stream>>>(Ap, Bp, Sh);
    log_red<<<dim3(96), dim3(512), 0, stream>>>(Sh, lp);
    final_asm<<<dim3(1), dim3(64), 0, stream>>>(angp, lp, out);
}

// Round 8
// 61.363 us; speedup vs baseline: 1.1316x; 1.1316x over previous
//
#include <hip/hip_runtime.h>
#include <math.h>

constexpr int BN = 8192;
constexpr int MN = 6;

// E = -T*log2(e)*d2 with T=2:  E = 2TL*g - TL*sq_i - TL*sq_j,  L=log2(e)
constexpr float TL    = 2.8853900817779268f;   // 2*log2(e)
constexpr float SCL_Z = 2.4022448795936154f;   // sqrt(2*T*L)

typedef __bf16 bf16_t;
typedef bf16_t bf16x8 __attribute__((ext_vector_type(8)));
typedef float f32x4 __attribute__((ext_vector_type(4)));

union PK { bf16_t h[8]; uint4 u; };

__device__ __forceinline__ bf16x8 frag_of(uint4 u) {
    return __builtin_bit_cast(bf16x8, u);
}

__device__ __host__ __forceinline__ int midx(int a, int b) {
    return 8 * a - (a * (a - 1)) / 2 + (b - a);   // upper-tri 8x8 packed
}

// Combined fragment store C: per 16-row tile, 4 octets of 16 uint4 (1024 B):
//   s0=zh  s1=zl  s2=a3  s3=b3
// A-frag octet perm {zh,zl,zh,a3} -> pa(g) = (g==3)?2:(g&1)
// B-frag octet perm {zh,zh,zl,b3} -> pb(g) = (g==3)?3:(g>>1)

// ---------------------------------------------------------------------------
// K0: blocks 0..191 -> pack fragments; 192..223 -> angle second moments.
// ---------------------------------------------------------------------------
__global__ __launch_bounds__(256) void prep_ang(const float* __restrict__ x,
                                                const float* __restrict__ ang,
                                                uint4* __restrict__ C,
                                                float* __restrict__ angp) {
    const int blk = blockIdx.x;
    const int tid = threadIdx.x;
    if (blk < 192) {
        int idx = blk * 256 + tid;
        int n = idx >> 13;
        int j = idx & (BN - 1);
        const float* p = x + (size_t)j * 48 + n * 8;

        PK zh, zl, a3, b3;
        float sq = 0.f;
#pragma unroll
        for (int k = 0; k < 8; ++k) {
            float v = p[k];
            sq = fmaf(v, v, sq);
            float z = SCL_Z * v;
            bf16_t h = (bf16_t)z;
            zh.h[k] = h;
            zl.h[k] = (bf16_t)(z - (float)h);
        }
        float s = -TL * sq;
        bf16_t sh = (bf16_t)s;
        bf16_t sl = (bf16_t)(s - (float)sh);
        bf16_t one = (bf16_t)1.0f, zero = (bf16_t)0.0f;
        a3.h[0] = one; a3.h[1] = one; a3.h[2] = sh;  a3.h[3] = sl;
        b3.h[0] = sh;  b3.h[1] = sl;  b3.h[2] = one; b3.h[3] = one;
#pragma unroll
        for (int k = 4; k < 8; ++k) { a3.h[k] = zero; b3.h[k] = zero; }

        size_t base = ((size_t)(n * 512 + (j >> 4))) * 64 + (j & 15);
        C[base +  0] = zh.u;
        C[base + 16] = zl.u;
        C[base + 32] = a3.u;
        C[base + 48] = b3.u;
    } else {
        const int i = (blk - 192) * 256 + tid;
        float v[8];
#pragma unroll
        for (int k = 0; k < 4; ++k) __sincosf(ang[i * 4 + k], &v[k], &v[4 + k]);
        float acc[44];
        int c = 0;
#pragma unroll
        for (int a = 0; a < 8; ++a)
#pragma unroll
            for (int bq = a; bq < 8; ++bq) acc[c++] = v[a] * v[bq];
#pragma unroll
        for (int a = 0; a < 8; ++a) acc[36 + a] = v[a];

#pragma unroll
        for (int q = 0; q < 44; ++q) {
            float s = acc[q];
            s += __shfl_xor(s, 1);  s += __shfl_xor(s, 2);
            s += __shfl_xor(s, 4);  s += __shfl_xor(s, 8);
            s += __shfl_xor(s, 16); s += __shfl_xor(s, 32);
            acc[q] = s;
        }
        __shared__ float sm[4][44];
        const int w = tid >> 6, lane = tid & 63;
        if (lane == 0)
#pragma unroll
            for (int q = 0; q < 44; ++q) sm[w][q] = acc[q];
        __syncthreads();
        if (tid < 44)
            angp[(blk - 192) * 44 + tid] =
                sm[0][tid] + sm[1][tid] + sm[2][tid] + sm[3][tid];
    }
}

// ---------------------------------------------------------------------------
// K1: symmetric sweep.  Block = (mode m, strip-pair sp, parity h); 768 blocks
// x 512 thr.  Strip s in {sp, 127-sp}: row tiles 4s..4s+3; wave w sweeps col
// tiles jt >= 4s+4 with jt == 2w+h (mod 16).  Each tile credited twice:
// colsum -> racc (rows of strip s), rowsum -> LDS cred[jt][16] (rows 16jt+c).
// cred rows are residue-partitioned across waves: race-free, no atomics.
// ---------------------------------------------------------------------------
__global__ __launch_bounds__(512, 6) void pair_sweep(const uint4* __restrict__ C,
                                                     float* __restrict__ colsumP,
                                                     unsigned short* __restrict__ credP) {
    const int tid  = threadIdx.x;
    const int lane = tid & 63;
    const int w    = __builtin_amdgcn_readfirstlane(tid >> 6);
    const int b    = blockIdx.x;
    const int m    = b >> 7;
    const int sp   = (b >> 1) & 63;
    const int h    = b & 1;
    const int rho  = 2 * w + h;

    __shared__ float cred[8192];      // [512 col-tiles][16 cols]
    __shared__ float smem[8][64];
    for (int q = tid; q < 8192; q += 512) cred[q] = 0.f;
    __syncthreads();

    const int g  = lane >> 4;
    const int pa = (g == 3) ? 2 : (g & 1);
    const int pb = (g == 3) ? 3 : (g >> 1);
    const int cl = lane & 15;
    const f32x4 z4 = {0.f, 0.f, 0.f, 0.f};
    const uint4* mbase = C + (size_t)m * 512 * 64;
    const uint4* bcol  = mbase + pb * 16 + cl;

#pragma unroll 1
    for (int sidx = 0; sidx < 2; ++sidx) {
        const int s = sidx ? (127 - sp) : sp;

        bf16x8 af[4];
#pragma unroll
        for (int t = 0; t < 4; ++t)
            af[t] = frag_of(mbase[(size_t)(4 * s + t) * 64 + pa * 16 + cl]);

        float racc[16];
#pragma unroll
        for (int q = 0; q < 16; ++q) racc[q] = 0.f;

        const int start = 4 * s + 4;
        const int first = start + (int)(((unsigned)(rho - start)) & 15u);
        const int f0 = (first < 512) ? first : 0;   // safe addr even if empty

        uint4 b0 = bcol[(size_t)f0 * 64];
        uint4 b1 = bcol[(size_t)(f0 + 16) * 64];
        for (int jt = first; jt < 512; jt += 16) {
            uint4 p0 = bcol[(size_t)(jt + 32) * 64];   // over-read stays in ws
            bf16x8 bf = frag_of(b0);
            float rsum = 0.f;
#pragma unroll
            for (int t = 0; t < 4; ++t) {
                f32x4 d = __builtin_amdgcn_mfma_f32_16x16x32_bf16(af[t], bf, z4, 0, 0, 0);
#pragma unroll
                for (int r = 0; r < 4; ++r) {
                    float e = __builtin_amdgcn_exp2f(d[r]);
                    racc[t * 4 + r] += e;
                    rsum += e;
                }
            }
            // rowsum: fold the 4 lane-groups -> per-col totals (all lanes)
            rsum += __shfl_xor(rsum, 16);
            rsum += __shfl_xor(rsum, 32);
            if (lane < 16) cred[jt * 16 + lane] += rsum;
            b0 = b1; b1 = p0;
        }

        // colsum: reduce over the 16 column lanes
#pragma unroll
        for (int q = 0; q < 16; ++q) {
            float v = racc[q];
            v += __shfl_xor(v, 1);
            v += __shfl_xor(v, 2);
            v += __shfl_xor(v, 4);
            v += __shfl_xor(v, 8);
            racc[q] = v;
        }
        if (cl == 0) {
#pragma unroll
            for (int t = 0; t < 4; ++t)
#pragma unroll
                for (int r = 0; r < 4; ++r)
                    smem[w][t * 16 + g * 4 + r] = racc[t * 4 + r];
        }
        __syncthreads();
        if (tid < 64) {
            float ssum = 0.f;
#pragma unroll
            for (int ww = 0; ww < 8; ++ww) ssum += smem[ww][tid];
            colsumP[(size_t)h * (MN * BN) + m * BN + s * 64 + tid] = ssum;
        }
        __syncthreads();
    }

    // flush this block's parity rows of cred as bf16 contributor slot
    for (int q = tid; q < 4096; q += 512) {
        int jt = 2 * (q >> 4) + h, c = q & 15;
        bf16_t v = (bf16_t)cred[jt * 16 + c];
        credP[((size_t)((m * 64 + sp) * 2 + h)) * 4096 + q] =
            __builtin_bit_cast(unsigned short, v);
    }
}

// ---------------------------------------------------------------------------
// K1b: intra-strip 4x4 diagonal wedges.  768 waves (192 blocks x 256 thr).
// Wave = (mode, strip s): all 16 ordered tile pairs in [4s,4s+4)^2, colsum
// only (covers both orderings), skipping the self-diagonal elements.
// ---------------------------------------------------------------------------
__global__ __launch_bounds__(256) void wedge(const uint4* __restrict__ C,
                                             float* __restrict__ wedgeP) {
    const int tid  = threadIdx.x;
    const int lane = tid & 63;
    const int wl   = tid >> 6;
    const int gw   = blockIdx.x * 4 + wl;   // 0..767
    const int m    = gw >> 7;
    const int s    = gw & 127;

    const int g  = lane >> 4;
    const int pa = (g == 3) ? 2 : (g & 1);
    const int pb = (g == 3) ? 3 : (g >> 1);
    const int cl = lane & 15;
    const int dd = cl - 4 * g;
    const f32x4 z4 = {0.f, 0.f, 0.f, 0.f};
    const uint4* mbase = C + (size_t)m * 512 * 64;

    bf16x8 af[4];
#pragma unroll
    for (int t = 0; t < 4; ++t)
        af[t] = frag_of(mbase[(size_t)(4 * s + t) * 64 + pa * 16 + cl]);

    float racc[16];
#pragma unroll
    for (int q = 0; q < 16; ++q) racc[q] = 0.f;

#pragma unroll
    for (int u = 0; u < 4; ++u) {
        bf16x8 bf = frag_of(mbase[(size_t)(4 * s + u) * 64 + pb * 16 + cl]);
#pragma unroll
        for (int t = 0; t < 4; ++t) {
            f32x4 d = __builtin_amdgcn_mfma_f32_16x16x32_bf16(af[t], bf, z4, 0, 0, 0);
#pragma unroll
            for (int r = 0; r < 4; ++r) {
                float e = __builtin_amdgcn_exp2f(d[r]);
                if (u == t) e = (dd == r) ? 0.f : e;   // skip self-pair
                racc[t * 4 + r] += e;
            }
        }
    }

#pragma unroll
    for (int q = 0; q < 16; ++q) {
        float v = racc[q];
        v += __shfl_xor(v, 1);
        v += __shfl_xor(v, 2);
        v += __shfl_xor(v, 4);
        v += __shfl_xor(v, 8);
        racc[q] = v;
    }

    __shared__ float smem[4][64];
    if (cl == 0) {
#pragma unroll
        for (int t = 0; t < 4; ++t)
#pragma unroll
            for (int r = 0; r < 4; ++r)
                smem[wl][t * 16 + g * 4 + r] = racc[t * 4 + r];
    }
    float val = smem[wl][lane];   // same-wave RAW: compiler inserts lgkmcnt
    wedgeP[(size_t)m * BN + s * 64 + lane] = val;
}

// ---------------------------------------------------------------------------
// K2: total row sums = wedge + 2 colsum halves + 64 bf16 credit slots;
// log, per-block partial sums.  96 blocks x 512 (16 blocks per mode).
// ---------------------------------------------------------------------------
__global__ __launch_bounds__(512) void log_red(const float* __restrict__ colsumP,
                                               const float* __restrict__ wedgeP,
                                               const unsigned short* __restrict__ credP,
                                               float* __restrict__ lp) {
    const int tid = threadIdx.x;
    const int idx = blockIdx.x * 512 + tid;
    const int m = idx >> 13;
    const int i = idx & (BN - 1);
    const int jt = i >> 4, c = i & 15;
    const int hh = jt & 1;
    const int q = (jt >> 1) * 16 + c;

    float v = wedgeP[idx] + colsumP[idx] + colsumP[MN * BN + idx];
    const unsigned short* base = credP + ((size_t)(m * 128 + hh)) * 4096 + q;
#pragma unroll 8
    for (int sp = 0; sp < 64; ++sp) {
        unsigned short u = base[(size_t)sp * 8192];
        v += (float)__builtin_bit_cast(bf16_t, u);
    }
    float lg = logf(v);
    lg += __shfl_xor(lg, 1);
    lg += __shfl_xor(lg, 2);
    lg += __shfl_xor(lg, 4);
    lg += __shfl_xor(lg, 8);
    lg += __shfl_xor(lg, 16);
    lg += __shfl_xor(lg, 32);
    __shared__ float sm[8];
    if ((tid & 63) == 0) sm[tid >> 6] = lg;
    __syncthreads();
    if (tid == 0) {
        float s = 0.f;
#pragma unroll
        for (int k = 0; k < 8; ++k) s += sm[k];
        lp[blockIdx.x] = s;
    }
}

// ---------------------------------------------------------------------------
// K3: final assembly — mu/cov/spread from moments, per-mode unif, outputs.
// ---------------------------------------------------------------------------
__global__ __launch_bounds__(64) void final_asm(const float* __restrict__ angp,
                                                const float* __restrict__ lp,
                                                float* __restrict__ out) {
    const int tid = threadIdx.x;
    __shared__ float mom[44];

    if (tid < 44) {
        float s = 0.f;
        for (int bk = 0; bk < 32; ++bk) s += angp[bk * 44 + tid];
        mom[tid] = s;
    }
    __syncthreads();

    if (tid == 0) {
        float sm[4], cm[4];
#pragma unroll
        for (int k = 0; k < 4; ++k) {
            float S = mom[36 + k], Cc = mom[40 + k];
            float hyp = sqrtf(S * S + Cc * Cc);
            sm[k] = S / hyp;
            cm[k] = Cc / hyp;
        }
        auto COV = [&](int k, int l) -> float {
            int ks = k < l ? k : l, kl = k < l ? l : k;
            float mss = mom[midx(ks, kl)];
            float msc_kl = mom[midx(k, l + 4)];
            float msc_lk = mom[midx(l, k + 4)];
            float mcc = mom[midx(ks + 4, kl + 4)];
            return (cm[k] * cm[l] * mss - cm[k] * sm[l] * msc_kl -
                    sm[k] * cm[l] * msc_lk + sm[k] * sm[l] * mcc) *
                   (1.0f / (float)BN);
        };
        float var[4] = {COV(0, 0), COV(1, 1), COV(2, 2), COV(3, 3)};
        float spread = 0.f;
        const int pk[6] = {0, 0, 0, 1, 1, 2};
        const int pl[6] = {1, 2, 3, 2, 3, 3};
#pragma unroll
        for (int p = 0; p < 6; ++p) {
            float cv = COV(pk[p], pl[p]);
            float den = sqrtf(var[pk[p]] * var[pl[p]] + 1e-8f);
            float cr = cv / den;
            spread += cr * cr;
        }
        spread *= (1.0f / 6.0f);

        const float wgt[6] = {0.0f, 0.19615242270663188f, 0.4641016151377544f,
                              0.7320508075688773f, 0.9282032302755088f, 1.0f};
        const float logBm1 = logf((float)(BN - 1));
        float total_unif = 0.f, unif[6];
#pragma unroll
        for (int mm = 0; mm < 6; ++mm) {
            float s = 0.f;
            for (int k = 0; k < 16; ++k) s += lp[mm * 16 + k];
            unif[mm] = s * (1.0f / (float)BN) - logBm1;
            total_unif += wgt[mm] * unif[mm];
        }
        out[0] = total_unif;
        out[1] = spread;
        out[2] = total_unif + spread;
#pragma unroll
        for (int mm = 0; mm < 6; ++mm) out[3 + mm] = unif[mm];
    }
}

extern "C" void kernel_launch(void* const* d_in, const int* in_sizes, int n_in,
                              void* d_out, int out_size, void* d_ws, size_t ws_size,
                              hipStream_t stream) {
    const float* angles  = (const float*)d_in[0];   // (8192, 4) f32
    const float* fourier = (const float*)d_in[1];   // (8192, 48) f32
    float* out = (float*)d_out;                     // 9 floats

    char* ws = (char*)d_ws;
    uint4* C              = (uint4*)(ws + 0);             // 3,145,728 B
    unsigned short* credP = (unsigned short*)(ws + 3145728);  // 6,291,456 B
    float* colsumP        = (float*)(ws + 9437184);       // 393,216 B
    float* wedgeP         = (float*)(ws + 9830400);       // 196,608 B
    float* lp             = (float*)(ws + 10027008);      // 384 B
    float* angp           = (float*)(ws + 10027392);      // 5,632 B

    prep_ang<<<dim3(224), dim3(256), 0, stream>>>(fourier, angles, C, angp);
    pair_sweep<<<dim3(768), dim3(512), 0, stream>>>(C, colsumP, credP);
    wedge<<<dim3(192), dim3(256), 0, stream>>>(C, wedgeP);
    log_red<<<dim3(96), dim3(512), 0, stream>>>(colsumP, wedgeP, credP, lp);
    final_asm<<<dim3(1), dim3(64), 0, stream>>>(angp, lp, out);
}